// Round 1
// 70.552 us; speedup vs baseline: 1.0226x; 1.0226x over previous
//
#include <hip/hip_runtime.h>
#include <math.h>

#define BETA 0.001f
#define WPB  4          // waves per block; one segment per wave

// softplus(x_j - x_i) (i<j) = 0.5*h(x_j-x_i) + 0.5*(x_j-x_i),
//   h(d) = |d| + 2*ln(1+e^{-|d|})
// Sum over pairs:
//   sum_{i<j} softplus = 0.25*(S_full - L*h(0)) + 0.5*sum_k x_k*(2k-L+1)
//   where S_full sums h over ALL ordered (i,j) incl. diagonal, h(0)=2 ln 2.
// l2 term separable: sum_pairs 0.5*(pos^2+neg^2) = 0.5*(L-1)*sum(x^2).
//
// Transcendental reduction: per chain accumulate
//   su = sum |d|,  p = prod (1 + e^{-|d|})   (factors in (1,2], <=127 of
//   them -> p <= 2^127 < FLT_MAX, no overflow possible)
// then  sum h = su + 2*ln2 * log2(p)  -> ONE v_log_f32 per chain total.
//
// v2 structural changes vs previous best (72 us):
//  * NO atomics, NO out-memset dispatch: main kernel plain-stores one
//    partial per segment into d_ws; a 1-block reduce kernel sums them and
//    plain-stores out (d_out poison is fully overwritten). This removes
//    the 1024 same-address device-scope atomicAdds (serialize across 8
//    non-coherent XCDs) and the extra fill-kernel graph node.
//  * LDS-free inner loop: x[j] is wave-uniform -> broadcast via
//    v_readlane_b32 (value lands in SGPR, free scalar operand), removing
//    the per-iteration ds_read + lgkmcnt wait, the staging writes, and
//    the block-level __syncthreads combine.

__device__ __forceinline__ float lane_bcast(float v, int lane_u) {
    // wave-uniform lane index -> v_readlane_b32 (no LDS, no lgkmcnt)
    return __uint_as_float(
        (unsigned)__builtin_amdgcn_readlane((int)__float_as_uint(v), lane_u));
}

__global__ __launch_bounds__(WPB * 64) void rmloss_part(
    const float* __restrict__ logits,
    const int*   __restrict__ cu,
    float*       __restrict__ part,   // [n_seg] partials (d_ws)
    int n_seg, float inv_n)
{
    const int wave = threadIdx.x >> 6;
    const int lane = threadIdx.x & 63;
    const int s = blockIdx.x * WPB + wave;
    if (s >= n_seg) return;            // wave-uniform; no barriers anywhere

    const int a   = cu[s];
    const int L   = cu[s + 1] - a;     // 32..127
    const int Lm1 = L - 1;

    const float kNL2E = -1.44269504088896340736f;  // -log2(e)
    const float kT2L2 =  1.38629436111989061883f;  //  2*ln(2)

    const bool a_ok = lane < L;
    const bool b_ok = lane + 64 < L;
    const float va = a_ok ? logits[a + lane] : 0.0f;
    const float vb = b_ok ? logits[a + lane + 64] : 0.0f;

    float su_a = 0.0f, p_a = 1.0f;
    float su_b = 0.0f, p_b = 1.0f;

    if (L > 64) {                       // all va lanes valid here
        #pragma unroll 4
        for (int j = 0; j < 64; ++j) {  // broadcast x[0..63] from va regs
            const float v  = lane_bcast(va, j);
            const float ua = fabsf(va - v);
            su_a += ua;
            p_a = fmaf(p_a, __builtin_amdgcn_exp2f(ua * kNL2E), p_a);
            const float ub = fabsf(vb - v);
            su_b += ub;
            p_b = fmaf(p_b, __builtin_amdgcn_exp2f(ub * kNL2E), p_b);
        }
        const int t2 = L - 64;          // 1..63
        #pragma unroll 4
        for (int j = 0; j < t2; ++j) {  // broadcast x[64..L-1] from vb regs
            const float v  = lane_bcast(vb, j);
            const float ua = fabsf(va - v);
            su_a += ua;
            p_a = fmaf(p_a, __builtin_amdgcn_exp2f(ua * kNL2E), p_a);
            const float ub = fabsf(vb - v);
            su_b += ub;
            p_b = fmaf(p_b, __builtin_amdgcn_exp2f(ub * kNL2E), p_b);
        }
    } else {
        #pragma unroll 4
        for (int j = 0; j < L; ++j) {
            const float v  = lane_bcast(va, j);
            const float ua = fabsf(va - v);
            su_a += ua;
            p_a = fmaf(p_a, __builtin_amdgcn_exp2f(ua * kNL2E), p_a);
        }
    }

    // one log2 per chain (v_log_f32 IS log2 on gfx950)
    const float ha = su_a + kT2L2 * __builtin_amdgcn_logf(p_a);
    const float hb = su_b + kT2L2 * __builtin_amdgcn_logf(p_b);
    const float acch = (a_ok ? ha : 0.0f) + (b_ok ? hb : 0.0f);

    const float lin = va * (float)(2 * lane - Lm1)
                    + vb * (float)(2 * (lane + 64) - Lm1);
    const float sq  = va * va + vb * vb;

    float f = 0.25f * acch + 0.5f * lin + (0.5f * BETA * (float)Lm1) * sq;
    #pragma unroll
    for (int off = 32; off > 0; off >>= 1)
        f += __shfl_down(f, off, 64);

    if (lane == 0) {
        const float P    = 0.5f * (float)(L * Lm1);
        const float diag = 0.25f * (float)L * kT2L2;  // 0.25*L*h(0)
        part[s] = (f - diag) / P * inv_n;
    }
}

// Single-block sum of the per-segment partials; plain store to out.
__global__ __launch_bounds__(256) void rmloss_reduce(
    const float* __restrict__ part, float* __restrict__ out, int n)
{
    const int t = threadIdx.x;
    float acc = 0.0f;

    const int n4 = n >> 2;
    const float4* __restrict__ p4 = (const float4*)part;
    for (int i = t; i < n4; i += 256) {
        const float4 v = p4[i];
        acc += (v.x + v.y) + (v.z + v.w);
    }
    for (int i = (n4 << 2) + t; i < n; i += 256)   // tail (none for 4096)
        acc += part[i];

    #pragma unroll
    for (int off = 32; off > 0; off >>= 1)
        acc += __shfl_down(acc, off, 64);

    __shared__ float ws[4];
    if ((t & 63) == 0) ws[t >> 6] = acc;
    __syncthreads();
    if (t == 0) out[0] = (ws[0] + ws[1]) + (ws[2] + ws[3]);
}

extern "C" void kernel_launch(void* const* d_in, const int* in_sizes, int n_in,
                              void* d_out, int out_size, void* d_ws, size_t ws_size,
                              hipStream_t stream) {
    (void)n_in; (void)out_size; (void)ws_size;

    const float* logits = (const float*)d_in[0];
    const int*   cu     = (const int*)d_in[1];
    float*       out    = (float*)d_out;
    float*       part   = (float*)d_ws;          // 4*n_seg = 16 KB of ws

    const int n_seg  = in_sizes[1] - 1;
    const int blocks = (n_seg + WPB - 1) / WPB;

    rmloss_part<<<blocks, WPB * 64, 0, stream>>>(logits, cu, part, n_seg,
                                                 1.0f / (float)n_seg);
    rmloss_reduce<<<1, 256, 0, stream>>>(part, out, n_seg);
}